// Round 15
// baseline (355.919 us; speedup 1.0000x reference)
//
#include <hip/hip_runtime.h>
#include <cstdint>
#include <cstddef>

#define BB 8
#define CC 64
#define NN 4096
#define OO 64
#define KK 20
#define TWO_C 128
#define BN (BB * NN)

#define GSPLIT 16            // j-range split for gmax (256 j per block)
#define GJPB (NN / GSPLIT)
#define JCH 128              // collect: j-chunk staged in LDS
#define CSPLIT 4             // j-range split for collect (= cand segments)
#define CJPB (NN / CSPLIT)
#define SEGCAP 32            // per-row per-segment capacity (R6-proven: never overflows here)

typedef float vf4 __attribute__((ext_vector_type(4)));
typedef float f4  __attribute__((ext_vector_type(4)));
typedef _Float16 hf2 __attribute__((ext_vector_type(2)));
typedef _Float16 h8  __attribute__((ext_vector_type(8)));

__device__ __forceinline__ unsigned int pack_h2(float a, float b) {
    hf2 h; h.x = (_Float16)a; h.y = (_Float16)b;
    return __builtin_bit_cast(unsigned int, h);
}

// Monotone float->uint map: a > b (float) <=> mu(a) > mu(b) (uint)
__device__ __forceinline__ unsigned int fmap(float d) {
    unsigned int s = __float_as_uint(d);
    return s ^ (unsigned int)(((int)s >> 31) | 0x80000000);
}

// Bitonic compare-exchange across lanes (u64 keys), direction per k-block.
__device__ __forceinline__ unsigned long long cmpx(unsigned long long key, int lane, int j, bool dirDesc) {
    unsigned long long o = __shfl_xor(key, j, 64);
    bool lower = (lane & j) == 0;
    bool takeMax = (dirDesc == lower);
    return ((o > key) == takeMax) ? o : key;
}

// ---------------- kernel 0: transpose + f16 packing (+ xx role, grid-concat) ----------------
// blockIdx.x < NN/64: transpose role. Else: xx role (squared norms) — removes
// a serial ~8us dispatch; both roles read only x; branch is block-uniform.
__global__ __launch_bounds__(256) void transpose_kernel(const float* __restrict__ x,
                                                        float* __restrict__ xT,
                                                        unsigned int* __restrict__ xTh,
                                                        float* __restrict__ xx) {
    __shared__ float t[64][65];
    const int tid = threadIdx.x;
    if (blockIdx.x >= NN / 64) {   // ---- xx role: 16 x-cols x 8 y = 128 blocks
        int q = (blockIdx.x - NN / 64) * BB + blockIdx.y;   // [0,128)
        int tt2 = q * 256 + tid;                            // [0, B*N)
        int b = tt2 >> 12, n = tt2 & (NN - 1);
        const float* xp = x + (size_t)b * CC * NN + n;
        float acc = 0.f;
#pragma unroll
        for (int c = 0; c < CC; ++c) {
            float v = xp[(size_t)c * NN];
            acc += v * v;
        }
        xx[tt2] = acc;
        return;
    }
    const int b = blockIdx.y;
    const int n0 = blockIdx.x * 64;
    const int ln = tid & 63, g = tid >> 6;
#pragma unroll
    for (int i = 0; i < 16; ++i) {
        int c = g * 16 + i;
        t[c][ln] = x[((size_t)b * CC + c) * NN + n0 + ln];
    }
    __syncthreads();
#pragma unroll
    for (int i = 0; i < 16; ++i) {
        int nl = g * 16 + i;
        xT[((size_t)b * NN + n0 + nl) * CC + ln] = t[ln][nl];
    }
#pragma unroll
    for (int it = 0; it < 8; ++it) {
        int e = it * 256 + tid;           // 0..2047
        int nl = e >> 5, cp = e & 31;
        xTh[((size_t)b * NN + n0 + nl) * 32 + cp] = pack_h2(t[2*cp][nl], t[2*cp+1][nl]);
    }
}

// ---------------- kernel 2a: LDS-free streaming MFMA -> per-row group maxima ----------------
// xTh (512 KB/batch) is L2-resident: stream B directly from global, no LDS, no
// barriers. Each wave owns 64 rows (4 A-sets) x 256 j (2 groups of 128).
// GSPLIT=16 -> 2048 blocks (8 blocks/CU): latency hidden by TLP.
__global__ __launch_bounds__(256) void knn_gmax_kernel(const unsigned int* __restrict__ xTh,
                                                       const float* __restrict__ xx,
                                                       float* __restrict__ gmaxG) {
    const int tid = threadIdx.x;
    const int wv = tid >> 6, lane = tid & 63;
    const int lcol = lane & 15, lrow = lane >> 4;
    const int b = blockIdx.z;
    const int i0w = blockIdx.x * 256 + wv * 64;   // this wave's 64 rows
    const int j0 = blockIdx.y * GJPB;             // 256 j
    const unsigned int* xb = xTh + (size_t)b * NN * 32;
    const float* xxb = xx + (size_t)b * NN;

    uint4 A0[4], A1[4];
#pragma unroll
    for (int s = 0; s < 4; ++s) {
        const uint4* ap = (const uint4*)(xb + (size_t)(i0w + s * 16 + lcol) * 32 + lrow * 4);
        A0[s] = ap[0]; A1[s] = ap[4];             // k 0..31 / 32..63
    }

    int g = j0 >> 7;
    for (int gg = 0; gg < GJPB / 128; ++gg, ++g) {
        float m[16];
#pragma unroll
        for (int s = 0; s < 16; ++s) m[s] = -3.4e38f;
#pragma unroll
        for (int jt = 0; jt < 8; ++jt) {
            const int jj = j0 + gg * 128 + jt * 16 + lcol;
            const uint4* bp = (const uint4*)(xb + (size_t)jj * 32 + lrow * 4);
            uint4 B0 = bp[0], B1 = bp[4];
            float h = 0.5f * xxb[jj];
#pragma unroll
            for (int s = 0; s < 4; ++s) {
                f4 acc = {0.f, 0.f, 0.f, 0.f};
                acc = __builtin_amdgcn_mfma_f32_16x16x32_f16(__builtin_bit_cast(h8, A0[s]), __builtin_bit_cast(h8, B0), acc, 0, 0, 0);
                acc = __builtin_amdgcn_mfma_f32_16x16x32_f16(__builtin_bit_cast(h8, A1[s]), __builtin_bit_cast(h8, B1), acc, 0, 0, 0);
#pragma unroll
                for (int r = 0; r < 4; ++r)
                    m[s * 4 + r] = fmaxf(m[s * 4 + r], acc[r] - h);
            }
        }
        // group of 128 j complete: reduce across the 16 lcol lanes, f4 stores
#pragma unroll
        for (int s = 0; s < 16; ++s) {
#pragma unroll
            for (int off = 1; off < 16; off <<= 1)
                m[s] = fmaxf(m[s], __shfl_xor(m[s], off));
        }
        if (lcol == 0) {
            int r0 = b * NN + i0w + lrow * 4;
#pragma unroll
            for (int s = 0; s < 4; ++s) {
                f4 mv; mv[0] = m[4*s]; mv[1] = m[4*s+1]; mv[2] = m[4*s+2]; mv[3] = m[4*s+3];
                *(f4*)&gmaxG[(size_t)g * BN + r0 + s * 16] = mv;
            }
        }
    }
}

// ---------------- kernel 2b: per-row threshold = 20th-largest of 32 group maxima ----------------
// Order-stat: the 20 group-maxima >= T are 20 distinct elements => T <= 20th-
// largest overall, so collecting d >= T can never miss a top-20 element.
__global__ __launch_bounds__(256) void knn_thresh_kernel(const float* __restrict__ gmaxG,
                                                         float* __restrict__ Tg) {
    const int row = blockIdx.x * 256 + threadIdx.x;   // [0, B*N)
    float L[KK];
#pragma unroll
    for (int s = 0; s < KK; ++s) L[s] = -3.4e38f;
#pragma unroll
    for (int g = 0; g < 32; ++g) {
        float xv = gmaxG[(size_t)g * BN + row];
#pragma unroll
        for (int s = 0; s < KK; ++s) {
            float hi = fmaxf(xv, L[s]);
            xv = fminf(xv, L[s]);
            L[s] = hi;
        }
    }
    Tg[row] = L[KK - 1];
}

// ---------------- kernel 2c: staged recompute + BALLOT collect of j with d >= T[row] ----------------
// R12's proven structure at higher occupancy: each wave owns 16 rows (1 A-set,
// s-loop removed), block = 64 rows -> grid 2048 (7 blocks/CU LDS-limited, was
// 4 hard cap at 33% occ / 53% VALUBusy). Uniform `if (mask)` skips the
// popc/store sequence for empty ballots (~62%: 64 (row,j) pairs at ~0.76% hit
// rate). Semantics identical: mask==0 => no store, cnt unchanged. cnt counts
// ALL hits; stores capped at SEGCAP -> overflow caught by merge's guard.
__global__ __launch_bounds__(256) void knn_collect_kernel(const unsigned int* __restrict__ xTh,
                                                          const float* __restrict__ xx,
                                                          const float* __restrict__ Tg,
                                                          unsigned short* __restrict__ cand,
                                                          unsigned int* __restrict__ cntS) {
    __shared__ unsigned int stage[JCH * 36];       // 18 KB: 128 j x 32 words, stride 36
    __shared__ float xxh[JCH];
    __shared__ unsigned short bufL[64][SEGCAP];    // 4 KB
    const int tid = threadIdx.x;
    const int wv = tid >> 6, lane = tid & 63;
    const int lcol = lane & 15, lrow = lane >> 4;
    const int b = blockIdx.z;
    const int i0 = blockIdx.x * 64;
    const int i0w = i0 + wv * 16;                  // this wave's 16 rows
    const int seg = blockIdx.y;
    const int j0 = seg * CJPB;                     // 1024 j
    const unsigned int* xb = xTh + (size_t)b * NN * 32;
    const float* xxb = xx + (size_t)b * NN;

    uint4 A0, A1;
    {
        const uint4* ap = (const uint4*)(xb + (size_t)(i0w + lcol) * 32 + lrow * 4);
        A0 = ap[0]; A1 = ap[4];
    }
    f4 tt = *(const f4*)&Tg[b * NN + i0w + lrow * 4];

    unsigned int cnt[4];
#pragma unroll
    for (int r = 0; r < 4; ++r) cnt[r] = 0;

    uint4 pf[4];
    float pxx;
    {
        const uint4* src = (const uint4*)(xb + (size_t)j0 * 32);
#pragma unroll
        for (int gi = 0; gi < 4; ++gi) pf[gi] = src[gi * 256 + tid];
        pxx = xxb[j0 + (tid & 127)];
    }

    for (int jc = j0; jc < j0 + CJPB; jc += JCH) {
        __syncthreads();   // prior chunk's readers done
#pragma unroll
        for (int gi = 0; gi < 4; ++gi) {
            int e4 = gi * 256 + tid;
            *(uint4*)&stage[(e4 >> 3) * 36 + (e4 & 7) * 4] = pf[gi];
        }
        if (tid < JCH) xxh[tid] = 0.5f * pxx;
        __syncthreads();   // stage ready
        if (jc + JCH < j0 + CJPB) {
            const uint4* src = (const uint4*)(xb + (size_t)(jc + JCH) * 32);
#pragma unroll
            for (int gi = 0; gi < 4; ++gi) pf[gi] = src[gi * 256 + tid];
            pxx = xxb[jc + JCH + (tid & 127)];
        }
#pragma unroll
        for (int jt = 0; jt < 8; ++jt) {
            const uint4* bp = (const uint4*)&stage[(jt * 16 + lcol) * 36 + lrow * 4];
            uint4 B0 = bp[0], B1 = bp[4];
            float h = xxh[jt * 16 + lcol];
            const int jj = jc + jt * 16 + lcol;
            f4 acc = {0.f, 0.f, 0.f, 0.f};
            acc = __builtin_amdgcn_mfma_f32_16x16x32_f16(__builtin_bit_cast(h8, A0), __builtin_bit_cast(h8, B0), acc, 0, 0, 0);
            acc = __builtin_amdgcn_mfma_f32_16x16x32_f16(__builtin_bit_cast(h8, A1), __builtin_bit_cast(h8, B1), acc, 0, 0, 0);
#pragma unroll
            for (int r = 0; r < 4; ++r) {
                bool hit = (acc[r] - h >= tt[r]);
                unsigned long long mask = __ballot(hit);
                if (mask) {   // wave-uniform skip of empty ballots
                    unsigned int grp = (unsigned int)(mask >> (lrow * 16)) & 0xFFFFu;
                    unsigned int pos = cnt[r] + (unsigned int)__popc(grp & ((1u << lcol) - 1u));
                    int rl = wv * 16 + lrow * 4 + r;
                    if (hit && pos < SEGCAP) bufL[rl][pos] = (unsigned short)jj;
                    cnt[r] += (unsigned int)__popc(grp);
                }
            }
        }
    }
    // per-row counts (uniform within each 16-lane group): lane lcol==0 writes
    if (lcol == 0) {
#pragma unroll
        for (int r = 0; r < 4; ++r)
            cntS[(size_t)seg * BN + b * NN + i0 + wv * 16 + lrow * 4 + r] = cnt[r];
    }
    __syncthreads();
    // coalesced copy-out of this block's private segment (64 rows x 32 shorts)
    const unsigned int* bl = (const unsigned int*)&bufL[0][0];
    unsigned int* cd = (unsigned int*)(cand + ((size_t)seg * BN + b * NN + i0) * SEGCAP);
#pragma unroll
    for (int e = tid; e < 64 * SEGCAP / 2; e += 256) cd[e] = bl[e];
}

// ---------------- kernel 2d: wave-per-row exact re-rank -> top-20 (R6 fused form) ----------------
// One 64-lane wave per row: lane l owns candidate l (one gather + 64 fmaf,
// fully parallel), then a 64-lane bitonic sort of total-order u64 keys
// (fmap(d)<<32 | 4095-j == lax.top_k tie semantics). Branchless single-load
// segment lookup. totals in (64,128] -> 2 keys/lane bitonic-128 (=4*SEGCAP
// max). Segment overflow -> exhaustive (never fires on this input: totals<=64
// [R3 measurement], segments<=32 [R6 measurement]).
__global__ __launch_bounds__(256) void knn_merge_kernel(const float* __restrict__ xT,
                                                        const float* __restrict__ xx,
                                                        const unsigned short* __restrict__ cand,
                                                        const unsigned int* __restrict__ cntS,
                                                        unsigned short* __restrict__ idx_out) {
    const int tid = threadIdx.x;
    const int wv = tid >> 6, lane = tid & 63;
    const int rr = __builtin_amdgcn_readfirstlane(blockIdx.x * 4 + wv);  // row [0, B*N)
    const int b = rr >> 12, i = rr & (NN - 1);
    const float* xTb = xT + (size_t)b * NN * CC;
    const float* xxb = xx + b * NN;

    vf4 xiv[CC / 4];
    const float* xip = xTb + (size_t)i * CC;
#pragma unroll
    for (int c4 = 0; c4 < CC / 4; ++c4) xiv[c4] = *(const vf4*)(xip + 4 * c4);

    unsigned int cs[CSPLIT];
    bool segovf = false;
    unsigned int total = 0;
#pragma unroll
    for (int s = 0; s < CSPLIT; ++s) {
        cs[s] = cntS[(size_t)s * BN + rr];
        segovf |= (cs[s] > SEGCAP);
        total += cs[s];
    }

    auto dot_key = [&](int jj) -> unsigned long long {
        const float* xj = xTb + (size_t)jj * CC;
        float a0 = 0.f, a1 = 0.f, a2 = 0.f, a3 = 0.f;
#pragma unroll
        for (int c4 = 0; c4 < CC / 4; ++c4) {
            vf4 xjv = *(const vf4*)(xj + 4 * c4);
            a0 = fmaf(xiv[c4].x, xjv.x, a0);
            a1 = fmaf(xiv[c4].y, xjv.y, a1);
            a2 = fmaf(xiv[c4].z, xjv.z, a2);
            a3 = fmaf(xiv[c4].w, xjv.w, a3);
        }
        float d = 2.f * ((a0 + a1) + (a2 + a3)) - xxb[jj];
        return ((unsigned long long)fmap(d) << 32) | (unsigned int)(NN - 1 - jj);
    };

    // Branchless: select-chain computes the flat cand offset, then ONE load.
    auto fetch_key = [&](unsigned int l) -> unsigned long long {
        if (l >= total) return 0ull;
        unsigned int base = 0, addr = 0;
#pragma unroll
        for (int s = 0; s < CSPLIT; ++s) {
            unsigned int lo = base;
            base += cs[s];
            unsigned int a = ((unsigned int)s * (unsigned int)BN + (unsigned int)rr) * SEGCAP + (l - lo);
            bool in = (l >= lo) & (l < base);
            addr = in ? a : addr;
        }
        return dot_key((int)cand[addr]);
    };

    unsigned long long kout;
    if (!segovf && total <= 64) {
        unsigned long long key = fetch_key((unsigned int)lane);
        // bitonic sort 64, descending
#pragma unroll
        for (int k = 2; k <= 64; k <<= 1) {
            bool dir = (lane & k) == 0;
#pragma unroll
            for (int j = k >> 1; j > 0; j >>= 1) key = cmpx(key, lane, j, dir);
        }
        kout = key;
    } else if (!segovf) {          // 64 < total <= 128 = CSPLIT*SEGCAP
        unsigned long long key  = fetch_key((unsigned int)lane);
        unsigned long long key2 = fetch_key((unsigned int)lane + 64);
        // bitonic sort 128 (elements: e = lane for key, e = 64+lane for key2)
#pragma unroll
        for (int k = 2; k <= 64; k <<= 1) {
            bool dir0 = (lane & k) == 0;
            bool dir1 = (k == 64) ? false : dir0;   // (e1 & 64) = 64 at k=64
#pragma unroll
            for (int j = k >> 1; j > 0; j >>= 1) {
                key  = cmpx(key,  lane, j, dir0);
                key2 = cmpx(key2, lane, j, dir1);
            }
        }
        // k = 128 (dir = descending for all): j = 64 is the in-lane pair
        {
            unsigned long long mx = key2 > key ? key2 : key;
            unsigned long long mn = key2 > key ? key : key2;
            key = mx; key2 = mn;
        }
#pragma unroll
        for (int j = 32; j > 0; j >>= 1) {
            key  = cmpx(key,  lane, j, true);
            key2 = cmpx(key2, lane, j, true);
        }
        kout = key;
    } else {
        // exhaustive: rounds of 64 j's; running top-64 in `run` (desc). Exact.
        unsigned long long run = 0ull;
        for (int t = 0; t < NN / 64; ++t) {
            unsigned long long key = dot_key(t * 64 + lane);
#pragma unroll
            for (int k = 2; k <= 64; k <<= 1) {
                bool dir = (lane & k) == 0;
#pragma unroll
                for (int j = k >> 1; j > 0; j >>= 1) key = cmpx(key, lane, j, dir);
            }
            // merge: [key desc | rev(run) asc] is bitonic-128; keep top half
            unsigned long long rev = __shfl(run, 63 - lane, 64);
            key = key > rev ? key : rev;
#pragma unroll
            for (int j = 32; j > 0; j >>= 1) key = cmpx(key, lane, j, true);
            run = key;
        }
        kout = run;
    }

    if (lane < KK)
        idx_out[(size_t)rr * KK + lane] =
            (unsigned short)(NN - 1 - (unsigned int)(kout & 0xFFFFFFFFull));
}

// ---------------- kernel 3: P = xt*W1^T, D = xt*(W2-W1)^T ----------------
// o split 4 ways (z=4): 16 outputs/thread (32 acc VGPR), grid 512 = 2/CU.
__global__ __launch_bounds__(256) void pd_kernel(const float* __restrict__ x,
                                                 const float* __restrict__ W,
                                                 float* __restrict__ P,
                                                 float* __restrict__ Dd) {
    __shared__ float w1T[CC][16];
    __shared__ float wdT[CC][16];
    const int tid = threadIdx.x;
    const int b = blockIdx.y;
    const int o0 = blockIdx.z * 16;
    for (int e = tid; e < 16 * CC; e += 256) {
        int ol = e >> 6, c = e & 63;
        float w1 = W[(o0 + ol) * TWO_C + c];
        float w2 = W[(o0 + ol) * TWO_C + CC + c];
        w1T[c][ol] = w1;
        wdT[c][ol] = w2 - w1;
    }
    __syncthreads();
    const int n = blockIdx.x * 256 + tid;
    float accp[16], accd[16];
#pragma unroll
    for (int i = 0; i < 16; ++i) { accp[i] = 0.f; accd[i] = 0.f; }
    const float* xp = x + (size_t)b * CC * NN + n;
    for (int c = 0; c < CC; ++c) {
        float xv = xp[(size_t)c * NN];
        const float4* w1r = (const float4*)&w1T[c][0];
        const float4* wdr = (const float4*)&wdT[c][0];
#pragma unroll
        for (int g = 0; g < 4; ++g) {
            float4 aw = w1r[g]; float4 bw = wdr[g];
            accp[4*g+0] += xv * aw.x; accp[4*g+1] += xv * aw.y;
            accp[4*g+2] += xv * aw.z; accp[4*g+3] += xv * aw.w;
            accd[4*g+0] += xv * bw.x; accd[4*g+1] += xv * bw.y;
            accd[4*g+2] += xv * bw.z; accd[4*g+3] += xv * bw.w;
        }
    }
    size_t base = ((size_t)b * NN + n) * OO + o0;
#pragma unroll
    for (int g = 0; g < 4; ++g) {
        *(float4*)&P[base + 4*g]  = make_float4(accp[4*g], accp[4*g+1], accp[4*g+2], accp[4*g+3]);
        *(float4*)&Dd[base + 4*g] = make_float4(accd[4*g], accd[4*g+1], accd[4*g+2], accd[4*g+3]);
    }
}

// ---------------- kernel 4: BN stats -> per-block partials ----------------
__global__ __launch_bounds__(256) void stats_kernel(const float* __restrict__ P,
                                                    const float* __restrict__ Dd,
                                                    const unsigned short* __restrict__ idx,
                                                    double* __restrict__ partials) {
    const int tid = threadIdx.x;
    const int o = tid & 63, g = tid >> 6;
    const int row0 = blockIdx.x * 32;
    double s1 = 0.0, s2 = 0.0;
    for (int i = 0; i < 8; ++i) {
        int row = row0 + g + 4 * i;
        int b = row >> 12;
        float d = Dd[(size_t)row * OO + o];
        const unsigned short* ip = idx + (size_t)row * KK;
        const float* Pb = P + ((size_t)b * NN) * OO;
#pragma unroll
        for (int k = 0; k < KK; ++k) {
            int j = ip[k];
            float y = Pb[(size_t)j * OO + o] + d;
            s1 += (double)y;
            s2 += (double)y * (double)y;
        }
    }
    __shared__ double r1[4][64];
    __shared__ double r2[4][64];
    r1[g][o] = s1; r2[g][o] = s2;
    __syncthreads();
    if (g == 0) {
        double a1 = r1[0][o] + r1[1][o] + r1[2][o] + r1[3][o];
        double a2 = r2[0][o] + r2[1][o] + r2[2][o] + r2[3][o];
        partials[(size_t)blockIdx.x * 128 + o]      = a1;
        partials[(size_t)blockIdx.x * 128 + 64 + o] = a2;
    }
}

// ---------------- kernel 5: reduce partials + finalize scale/shift ----------------
#define NSTATB (BB * NN / 32)
__global__ void finalize_kernel(const double* __restrict__ partials,
                                const float* __restrict__ gamma,
                                const float* __restrict__ beta,
                                float* __restrict__ ss) {
    int o = threadIdx.x;  // 64 threads
    double s1 = 0.0, s2 = 0.0;
    for (int blk = 0; blk < NSTATB; ++blk) {
        s1 += partials[(size_t)blk * 128 + o];
        s2 += partials[(size_t)blk * 128 + 64 + o];
    }
    const double cnt = (double)BB * NN * KK;
    double mean = s1 / cnt;
    double var = s2 / cnt - mean * mean;
    double rs = 1.0 / sqrt(var + 1e-5);
    double sc = (double)gamma[o] * rs;
    ss[o] = (float)sc;
    ss[64 + o] = (float)((double)beta[o] - mean * sc);
}

// ---------------- kernel 6: gather + BN affine + LeakyReLU + max_k + transpose ----------------
__global__ __launch_bounds__(256) void out_kernel(const float* __restrict__ P,
                                                  const float* __restrict__ Dd,
                                                  const unsigned short* __restrict__ idx,
                                                  const float* __restrict__ ss,
                                                  float* __restrict__ out) {
    __shared__ float tile[32][65];
    const int tid = threadIdx.x;
    const int o = tid & 63, g = tid >> 6;
    const int b = blockIdx.y;
    const int n0 = blockIdx.x * 32;
    const float sc = ss[o], sh = ss[64 + o];
    const float* Pb = P + ((size_t)b * NN) * OO;
    for (int i = 0; i < 8; ++i) {
        int nl = g + 4 * i;
        int row = b * NN + n0 + nl;
        float d = Dd[(size_t)row * OO + o];
        const unsigned short* ip = idx + (size_t)row * KK;
        float mv = -__builtin_inff();
#pragma unroll
        for (int k = 0; k < KK; ++k) {
            int j = ip[k];
            float y = Pb[(size_t)j * OO + o] + d;
            float t = y * sc + sh;
            t = (t >= 0.f) ? t : 0.2f * t;
            mv = fmaxf(mv, t);
        }
        tile[nl][o] = mv;
    }
    __syncthreads();
    const int nn = tid & 31, og = tid >> 5;   // 8 o-rows per pass
    for (int i = 0; i < 8; ++i) {
        int oo = og + 8 * i;
        out[((size_t)b * OO + oo) * NN + n0 + nn] = tile[nn][oo];
    }
}

// ---------------- launch ----------------
extern "C" void kernel_launch(void* const* d_in, const int* in_sizes, int n_in,
                              void* d_out, int out_size, void* d_ws, size_t ws_size,
                              hipStream_t stream) {
    (void)in_sizes; (void)n_in; (void)out_size; (void)ws_size;
    const float* x     = (const float*)d_in[0];   // [B, C, N]
    const float* W     = (const float*)d_in[1];   // [O, 2C]
    const float* gamma = (const float*)d_in[2];   // [O]
    const float* beta  = (const float*)d_in[3];   // [O]
    float* out = (float*)d_out;                   // [B, O, N] fp32

    // Workspace, phase-overlapped (peak ~22.2 MB):
    //   xx       @ 0           128 KB  (transpose -> merge)
    //   xT       @ 131,072     8 MB    (transpose -> merge)  -> P        (pd -> end)
    //   xTh      @ 8,519,680   4 MB    (transpose -> collect)-> idx      (merge -> end)
    //   gmaxG    @ 12,713,984  4 MB    (gmax -> thresh)
    //   cand     @ 12,713,984  8 MB    (collect -> merge)    -> Dd       (pd -> end)
    //   Tg       @ 21,102,592  128 KB  (thresh -> collect)   -> partials (stats ..)
    //   cntS     @ 21,233,664  512 KB  (collect -> merge)    -> partials
    //   ss       @ 22,151,168  512 B
    char* ws = (char*)d_ws;
    float*          xx       = (float*)ws;
    float*          xT       = (float*)(ws + 131072);
    unsigned int*   xTh      = (unsigned int*)(ws + 8519680);
    float*          gmaxG    = (float*)(ws + 12713984);
    unsigned short* cand     = (unsigned short*)(ws + 12713984);
    float*          Tg       = (float*)(ws + 21102592);
    unsigned int*   cntS     = (unsigned int*)(ws + 21233664);
    unsigned short* idx      = (unsigned short*)(ws + 8519680);
    float*          P        = (float*)(ws + 131072);
    float*          Dd       = (float*)(ws + 12713984);
    double*         partials = (double*)(ws + 21102592);
    float*          ss       = (float*)(ws + 22151168);

    transpose_kernel<<<dim3(NN / 64 + 16, BB), 256, 0, stream>>>(x, xT, xTh, xx);
    knn_gmax_kernel<<<dim3(NN / 256, GSPLIT, BB), 256, 0, stream>>>(xTh, xx, gmaxG);
    knn_thresh_kernel<<<dim3(BN / 256), 256, 0, stream>>>(gmaxG, Tg);
    knn_collect_kernel<<<dim3(NN / 64, CSPLIT, BB), 256, 0, stream>>>(xTh, xx, Tg, cand, cntS);
    knn_merge_kernel<<<dim3(BN / 4), 256, 0, stream>>>(xT, xx, cand, cntS, idx);
    pd_kernel<<<dim3(NN / 256, BB, 4), 256, 0, stream>>>(x, W, P, Dd);
    stats_kernel<<<dim3(BN / 32), 256, 0, stream>>>(P, Dd, idx, partials);
    finalize_kernel<<<1, 64, 0, stream>>>(partials, gamma, beta, ss);
    out_kernel<<<dim3(NN / 32, BB), 256, 0, stream>>>(P, Dd, idx, ss, out);
}

// Round 16
// 325.249 us; speedup vs baseline: 1.0943x; 1.0943x over previous
//
#include <hip/hip_runtime.h>
#include <cstdint>
#include <cstddef>

#define BB 8
#define CC 64
#define NN 4096
#define OO 64
#define KK 20
#define TWO_C 128
#define BN (BB * NN)

#define GSPLIT 16            // j-range split for gmax (256 j per block)
#define GJPB (NN / GSPLIT)
#define JCH 128              // collect: j-chunk staged in LDS
#define CSPLIT 4             // j-range split for collect (= cand segments)
#define CJPB (NN / CSPLIT)
#define SEGCAP 32            // per-row per-segment capacity (R6-proven: never overflows here)

typedef float vf4 __attribute__((ext_vector_type(4)));
typedef float f4  __attribute__((ext_vector_type(4)));
typedef _Float16 hf2 __attribute__((ext_vector_type(2)));
typedef _Float16 h8  __attribute__((ext_vector_type(8)));

__device__ __forceinline__ unsigned int pack_h2(float a, float b) {
    hf2 h; h.x = (_Float16)a; h.y = (_Float16)b;
    return __builtin_bit_cast(unsigned int, h);
}

// Monotone float->uint map: a > b (float) <=> mu(a) > mu(b) (uint)
__device__ __forceinline__ unsigned int fmap(float d) {
    unsigned int s = __float_as_uint(d);
    return s ^ (unsigned int)(((int)s >> 31) | 0x80000000);
}

// Bitonic compare-exchange across lanes (u64 keys), direction per k-block.
__device__ __forceinline__ unsigned long long cmpx(unsigned long long key, int lane, int j, bool dirDesc) {
    unsigned long long o = __shfl_xor(key, j, 64);
    bool lower = (lane & j) == 0;
    bool takeMax = (dirDesc == lower);
    return ((o > key) == takeMax) ? o : key;
}

// ---------------- kernel 0: transpose + f16 packing (+ xx role, grid-concat) ----------------
// blockIdx.x < NN/64: transpose role. Else: xx role (squared norms) — removes
// a serial ~8us dispatch; both roles read only x; branch is block-uniform.
__global__ __launch_bounds__(256) void transpose_kernel(const float* __restrict__ x,
                                                        float* __restrict__ xT,
                                                        unsigned int* __restrict__ xTh,
                                                        float* __restrict__ xx) {
    __shared__ float t[64][65];
    const int tid = threadIdx.x;
    if (blockIdx.x >= NN / 64) {   // ---- xx role: 16 x-cols x 8 y = 128 blocks
        int q = (blockIdx.x - NN / 64) * BB + blockIdx.y;   // [0,128)
        int tt2 = q * 256 + tid;                            // [0, B*N)
        int b = tt2 >> 12, n = tt2 & (NN - 1);
        const float* xp = x + (size_t)b * CC * NN + n;
        float acc = 0.f;
#pragma unroll
        for (int c = 0; c < CC; ++c) {
            float v = xp[(size_t)c * NN];
            acc += v * v;
        }
        xx[tt2] = acc;
        return;
    }
    const int b = blockIdx.y;
    const int n0 = blockIdx.x * 64;
    const int ln = tid & 63, g = tid >> 6;
#pragma unroll
    for (int i = 0; i < 16; ++i) {
        int c = g * 16 + i;
        t[c][ln] = x[((size_t)b * CC + c) * NN + n0 + ln];
    }
    __syncthreads();
#pragma unroll
    for (int i = 0; i < 16; ++i) {
        int nl = g * 16 + i;
        xT[((size_t)b * NN + n0 + nl) * CC + ln] = t[ln][nl];
    }
#pragma unroll
    for (int it = 0; it < 8; ++it) {
        int e = it * 256 + tid;           // 0..2047
        int nl = e >> 5, cp = e & 31;
        xTh[((size_t)b * NN + n0 + nl) * 32 + cp] = pack_h2(t[2*cp][nl], t[2*cp+1][nl]);
    }
}

// ---------------- kernel 2a: LDS-free streaming MFMA -> per-row group maxima ----------------
// xTh (512 KB/batch) is L2-resident: stream B directly from global, no LDS, no
// barriers. Each wave owns 64 rows (4 A-sets) x 256 j (2 groups of 128).
// GSPLIT=16 -> 2048 blocks (8 blocks/CU): latency hidden by TLP.
__global__ __launch_bounds__(256) void knn_gmax_kernel(const unsigned int* __restrict__ xTh,
                                                       const float* __restrict__ xx,
                                                       float* __restrict__ gmaxG) {
    const int tid = threadIdx.x;
    const int wv = tid >> 6, lane = tid & 63;
    const int lcol = lane & 15, lrow = lane >> 4;
    const int b = blockIdx.z;
    const int i0w = blockIdx.x * 256 + wv * 64;   // this wave's 64 rows
    const int j0 = blockIdx.y * GJPB;             // 256 j
    const unsigned int* xb = xTh + (size_t)b * NN * 32;
    const float* xxb = xx + (size_t)b * NN;

    uint4 A0[4], A1[4];
#pragma unroll
    for (int s = 0; s < 4; ++s) {
        const uint4* ap = (const uint4*)(xb + (size_t)(i0w + s * 16 + lcol) * 32 + lrow * 4);
        A0[s] = ap[0]; A1[s] = ap[4];             // k 0..31 / 32..63
    }

    int g = j0 >> 7;
    for (int gg = 0; gg < GJPB / 128; ++gg, ++g) {
        float m[16];
#pragma unroll
        for (int s = 0; s < 16; ++s) m[s] = -3.4e38f;
#pragma unroll
        for (int jt = 0; jt < 8; ++jt) {
            const int jj = j0 + gg * 128 + jt * 16 + lcol;
            const uint4* bp = (const uint4*)(xb + (size_t)jj * 32 + lrow * 4);
            uint4 B0 = bp[0], B1 = bp[4];
            float h = 0.5f * xxb[jj];
#pragma unroll
            for (int s = 0; s < 4; ++s) {
                f4 acc = {0.f, 0.f, 0.f, 0.f};
                acc = __builtin_amdgcn_mfma_f32_16x16x32_f16(__builtin_bit_cast(h8, A0[s]), __builtin_bit_cast(h8, B0), acc, 0, 0, 0);
                acc = __builtin_amdgcn_mfma_f32_16x16x32_f16(__builtin_bit_cast(h8, A1[s]), __builtin_bit_cast(h8, B1), acc, 0, 0, 0);
#pragma unroll
                for (int r = 0; r < 4; ++r)
                    m[s * 4 + r] = fmaxf(m[s * 4 + r], acc[r] - h);
            }
        }
        // group of 128 j complete: reduce across the 16 lcol lanes, f4 stores
#pragma unroll
        for (int s = 0; s < 16; ++s) {
#pragma unroll
            for (int off = 1; off < 16; off <<= 1)
                m[s] = fmaxf(m[s], __shfl_xor(m[s], off));
        }
        if (lcol == 0) {
            int r0 = b * NN + i0w + lrow * 4;
#pragma unroll
            for (int s = 0; s < 4; ++s) {
                f4 mv; mv[0] = m[4*s]; mv[1] = m[4*s+1]; mv[2] = m[4*s+2]; mv[3] = m[4*s+3];
                *(f4*)&gmaxG[(size_t)g * BN + r0 + s * 16] = mv;
            }
        }
    }
}

// ---------------- kernel 2b: per-row threshold = 20th-largest of 32 group maxima ----------------
// Order-stat: the 20 group-maxima >= T are 20 distinct elements => T <= 20th-
// largest overall, so collecting d >= T can never miss a top-20 element.
__global__ __launch_bounds__(256) void knn_thresh_kernel(const float* __restrict__ gmaxG,
                                                         float* __restrict__ Tg) {
    const int row = blockIdx.x * 256 + threadIdx.x;   // [0, B*N)
    float L[KK];
#pragma unroll
    for (int s = 0; s < KK; ++s) L[s] = -3.4e38f;
#pragma unroll
    for (int g = 0; g < 32; ++g) {
        float xv = gmaxG[(size_t)g * BN + row];
#pragma unroll
        for (int s = 0; s < KK; ++s) {
            float hi = fmaxf(xv, L[s]);
            xv = fminf(xv, L[s]);
            L[s] = hi;
        }
    }
    Tg[row] = L[KK - 1];
}

// ---------------- kernel 2c: staged recompute + BALLOT collect of j with d >= T[row] ----------------
// R14's proven code (69us, VGPR 44, occ 33%) + ONE change: wave-uniform
// `if (mask)` skips the popc/position/store/count sequence for empty ballots
// (~61%: 64 (row,j) pairs/ballot at ~0.76% hit rate; mask==0 => grp==0 => no
// store, cnt unchanged — semantics identical). R15's 64-row variant (100us)
// showed staging amortization dominates occupancy: keep 128 rows/block.
__global__ __launch_bounds__(256) void knn_collect_kernel(const unsigned int* __restrict__ xTh,
                                                          const float* __restrict__ xx,
                                                          const float* __restrict__ Tg,
                                                          unsigned short* __restrict__ cand,
                                                          unsigned int* __restrict__ cntS) {
    __shared__ unsigned int stage[JCH * 36];       // 18 KB: 128 j x 32 words, stride 36
    __shared__ float xxh[JCH];
    __shared__ unsigned short bufL[128][SEGCAP];   // 8 KB
    const int tid = threadIdx.x;
    const int wv = tid >> 6, lane = tid & 63;
    const int lcol = lane & 15, lrow = lane >> 4;
    const int b = blockIdx.z;
    const int i0 = blockIdx.x * 128;
    const int i0w = i0 + wv * 32;
    const int seg = blockIdx.y;
    const int j0 = seg * CJPB;                     // 1024 j
    const unsigned int* xb = xTh + (size_t)b * NN * 32;
    const float* xxb = xx + (size_t)b * NN;

    uint4 A0[2], A1[2];
    f4 tt[2];
#pragma unroll
    for (int s = 0; s < 2; ++s) {
        const uint4* ap = (const uint4*)(xb + (size_t)(i0w + s * 16 + lcol) * 32 + lrow * 4);
        A0[s] = ap[0]; A1[s] = ap[4];
        tt[s] = *(const f4*)&Tg[b * NN + i0w + s * 16 + lrow * 4];
    }

    unsigned int cnt[2][4];
#pragma unroll
    for (int s = 0; s < 2; ++s)
#pragma unroll
        for (int r = 0; r < 4; ++r) cnt[s][r] = 0;

    uint4 pf[4];
    float pxx;
    {
        const uint4* src = (const uint4*)(xb + (size_t)j0 * 32);
#pragma unroll
        for (int gi = 0; gi < 4; ++gi) pf[gi] = src[gi * 256 + tid];
        pxx = xxb[j0 + (tid & 127)];
    }

    for (int jc = j0; jc < j0 + CJPB; jc += JCH) {
        __syncthreads();   // prior chunk's readers done
#pragma unroll
        for (int gi = 0; gi < 4; ++gi) {
            int e4 = gi * 256 + tid;
            *(uint4*)&stage[(e4 >> 3) * 36 + (e4 & 7) * 4] = pf[gi];
        }
        if (tid < JCH) xxh[tid] = 0.5f * pxx;
        __syncthreads();   // stage ready
        if (jc + JCH < j0 + CJPB) {
            const uint4* src = (const uint4*)(xb + (size_t)(jc + JCH) * 32);
#pragma unroll
            for (int gi = 0; gi < 4; ++gi) pf[gi] = src[gi * 256 + tid];
            pxx = xxb[jc + JCH + (tid & 127)];
        }
#pragma unroll
        for (int jt = 0; jt < 8; ++jt) {
            const uint4* bp = (const uint4*)&stage[(jt * 16 + lcol) * 36 + lrow * 4];
            uint4 B0 = bp[0], B1 = bp[4];
            float h = xxh[jt * 16 + lcol];
            const int jj = jc + jt * 16 + lcol;
#pragma unroll
            for (int s = 0; s < 2; ++s) {
                f4 acc = {0.f, 0.f, 0.f, 0.f};
                acc = __builtin_amdgcn_mfma_f32_16x16x32_f16(__builtin_bit_cast(h8, A0[s]), __builtin_bit_cast(h8, B0), acc, 0, 0, 0);
                acc = __builtin_amdgcn_mfma_f32_16x16x32_f16(__builtin_bit_cast(h8, A1[s]), __builtin_bit_cast(h8, B1), acc, 0, 0, 0);
#pragma unroll
                for (int r = 0; r < 4; ++r) {
                    bool hit = (acc[r] - h >= tt[s][r]);
                    unsigned long long mask = __ballot(hit);
                    if (mask) {   // wave-uniform skip of empty ballots (~61%)
                        unsigned int grp = (unsigned int)(mask >> (lrow * 16)) & 0xFFFFu;
                        unsigned int pos = cnt[s][r] + (unsigned int)__popc(grp & ((1u << lcol) - 1u));
                        int rl = wv * 32 + s * 16 + lrow * 4 + r;
                        if (hit && pos < SEGCAP) bufL[rl][pos] = (unsigned short)jj;
                        cnt[s][r] += (unsigned int)__popc(grp);
                    }
                }
            }
        }
    }
    // per-row counts (uniform within each 16-lane group): lane lcol==0 writes
    if (lcol == 0) {
#pragma unroll
        for (int s = 0; s < 2; ++s)
#pragma unroll
            for (int r = 0; r < 4; ++r)
                cntS[(size_t)seg * BN + b * NN + i0 + wv * 32 + s * 16 + lrow * 4 + r] = cnt[s][r];
    }
    __syncthreads();
    // coalesced copy-out of this block's private segment (128 rows x 32 shorts)
    const unsigned int* bl = (const unsigned int*)&bufL[0][0];
    unsigned int* cd = (unsigned int*)(cand + ((size_t)seg * BN + b * NN + i0) * SEGCAP);
#pragma unroll
    for (int e = tid; e < 128 * SEGCAP / 2; e += 256) cd[e] = bl[e];
}

// ---------------- kernel 2d: wave-per-row exact re-rank -> top-20 (R6 fused form) ----------------
// One 64-lane wave per row: lane l owns candidate l (one gather + 64 fmaf,
// fully parallel), then a 64-lane bitonic sort of total-order u64 keys
// (fmap(d)<<32 | 4095-j == lax.top_k tie semantics). Branchless single-load
// segment lookup. totals in (64,128] -> 2 keys/lane bitonic-128 (=4*SEGCAP
// max). Segment overflow -> exhaustive (never fires on this input: totals<=64
// [R3 measurement], segments<=32 [R6 measurement]).
__global__ __launch_bounds__(256) void knn_merge_kernel(const float* __restrict__ xT,
                                                        const float* __restrict__ xx,
                                                        const unsigned short* __restrict__ cand,
                                                        const unsigned int* __restrict__ cntS,
                                                        unsigned short* __restrict__ idx_out) {
    const int tid = threadIdx.x;
    const int wv = tid >> 6, lane = tid & 63;
    const int rr = __builtin_amdgcn_readfirstlane(blockIdx.x * 4 + wv);  // row [0, B*N)
    const int b = rr >> 12, i = rr & (NN - 1);
    const float* xTb = xT + (size_t)b * NN * CC;
    const float* xxb = xx + b * NN;

    vf4 xiv[CC / 4];
    const float* xip = xTb + (size_t)i * CC;
#pragma unroll
    for (int c4 = 0; c4 < CC / 4; ++c4) xiv[c4] = *(const vf4*)(xip + 4 * c4);

    unsigned int cs[CSPLIT];
    bool segovf = false;
    unsigned int total = 0;
#pragma unroll
    for (int s = 0; s < CSPLIT; ++s) {
        cs[s] = cntS[(size_t)s * BN + rr];
        segovf |= (cs[s] > SEGCAP);
        total += cs[s];
    }

    auto dot_key = [&](int jj) -> unsigned long long {
        const float* xj = xTb + (size_t)jj * CC;
        float a0 = 0.f, a1 = 0.f, a2 = 0.f, a3 = 0.f;
#pragma unroll
        for (int c4 = 0; c4 < CC / 4; ++c4) {
            vf4 xjv = *(const vf4*)(xj + 4 * c4);
            a0 = fmaf(xiv[c4].x, xjv.x, a0);
            a1 = fmaf(xiv[c4].y, xjv.y, a1);
            a2 = fmaf(xiv[c4].z, xjv.z, a2);
            a3 = fmaf(xiv[c4].w, xjv.w, a3);
        }
        float d = 2.f * ((a0 + a1) + (a2 + a3)) - xxb[jj];
        return ((unsigned long long)fmap(d) << 32) | (unsigned int)(NN - 1 - jj);
    };

    // Branchless: select-chain computes the flat cand offset, then ONE load.
    auto fetch_key = [&](unsigned int l) -> unsigned long long {
        if (l >= total) return 0ull;
        unsigned int base = 0, addr = 0;
#pragma unroll
        for (int s = 0; s < CSPLIT; ++s) {
            unsigned int lo = base;
            base += cs[s];
            unsigned int a = ((unsigned int)s * (unsigned int)BN + (unsigned int)rr) * SEGCAP + (l - lo);
            bool in = (l >= lo) & (l < base);
            addr = in ? a : addr;
        }
        return dot_key((int)cand[addr]);
    };

    unsigned long long kout;
    if (!segovf && total <= 64) {
        unsigned long long key = fetch_key((unsigned int)lane);
        // bitonic sort 64, descending
#pragma unroll
        for (int k = 2; k <= 64; k <<= 1) {
            bool dir = (lane & k) == 0;
#pragma unroll
            for (int j = k >> 1; j > 0; j >>= 1) key = cmpx(key, lane, j, dir);
        }
        kout = key;
    } else if (!segovf) {          // 64 < total <= 128 = CSPLIT*SEGCAP
        unsigned long long key  = fetch_key((unsigned int)lane);
        unsigned long long key2 = fetch_key((unsigned int)lane + 64);
        // bitonic sort 128 (elements: e = lane for key, e = 64+lane for key2)
#pragma unroll
        for (int k = 2; k <= 64; k <<= 1) {
            bool dir0 = (lane & k) == 0;
            bool dir1 = (k == 64) ? false : dir0;   // (e1 & 64) = 64 at k=64
#pragma unroll
            for (int j = k >> 1; j > 0; j >>= 1) {
                key  = cmpx(key,  lane, j, dir0);
                key2 = cmpx(key2, lane, j, dir1);
            }
        }
        // k = 128 (dir = descending for all): j = 64 is the in-lane pair
        {
            unsigned long long mx = key2 > key ? key2 : key;
            unsigned long long mn = key2 > key ? key : key2;
            key = mx; key2 = mn;
        }
#pragma unroll
        for (int j = 32; j > 0; j >>= 1) {
            key  = cmpx(key,  lane, j, true);
            key2 = cmpx(key2, lane, j, true);
        }
        kout = key;
    } else {
        // exhaustive: rounds of 64 j's; running top-64 in `run` (desc). Exact.
        unsigned long long run = 0ull;
        for (int t = 0; t < NN / 64; ++t) {
            unsigned long long key = dot_key(t * 64 + lane);
#pragma unroll
            for (int k = 2; k <= 64; k <<= 1) {
                bool dir = (lane & k) == 0;
#pragma unroll
                for (int j = k >> 1; j > 0; j >>= 1) key = cmpx(key, lane, j, dir);
            }
            // merge: [key desc | rev(run) asc] is bitonic-128; keep top half
            unsigned long long rev = __shfl(run, 63 - lane, 64);
            key = key > rev ? key : rev;
#pragma unroll
            for (int j = 32; j > 0; j >>= 1) key = cmpx(key, lane, j, true);
            run = key;
        }
        kout = run;
    }

    if (lane < KK)
        idx_out[(size_t)rr * KK + lane] =
            (unsigned short)(NN - 1 - (unsigned int)(kout & 0xFFFFFFFFull));
}

// ---------------- kernel 3: P = xt*W1^T, D = xt*(W2-W1)^T ----------------
// o split 4 ways (z=4): 16 outputs/thread (32 acc VGPR), grid 512 = 2/CU.
__global__ __launch_bounds__(256) void pd_kernel(const float* __restrict__ x,
                                                 const float* __restrict__ W,
                                                 float* __restrict__ P,
                                                 float* __restrict__ Dd) {
    __shared__ float w1T[CC][16];
    __shared__ float wdT[CC][16];
    const int tid = threadIdx.x;
    const int b = blockIdx.y;
    const int o0 = blockIdx.z * 16;
    for (int e = tid; e < 16 * CC; e += 256) {
        int ol = e >> 6, c = e & 63;
        float w1 = W[(o0 + ol) * TWO_C + c];
        float w2 = W[(o0 + ol) * TWO_C + CC + c];
        w1T[c][ol] = w1;
        wdT[c][ol] = w2 - w1;
    }
    __syncthreads();
    const int n = blockIdx.x * 256 + tid;
    float accp[16], accd[16];
#pragma unroll
    for (int i = 0; i < 16; ++i) { accp[i] = 0.f; accd[i] = 0.f; }
    const float* xp = x + (size_t)b * CC * NN + n;
    for (int c = 0; c < CC; ++c) {
        float xv = xp[(size_t)c * NN];
        const float4* w1r = (const float4*)&w1T[c][0];
        const float4* wdr = (const float4*)&wdT[c][0];
#pragma unroll
        for (int g = 0; g < 4; ++g) {
            float4 aw = w1r[g]; float4 bw = wdr[g];
            accp[4*g+0] += xv * aw.x; accp[4*g+1] += xv * aw.y;
            accp[4*g+2] += xv * aw.z; accp[4*g+3] += xv * aw.w;
            accd[4*g+0] += xv * bw.x; accd[4*g+1] += xv * bw.y;
            accd[4*g+2] += xv * bw.z; accd[4*g+3] += xv * bw.w;
        }
    }
    size_t base = ((size_t)b * NN + n) * OO + o0;
#pragma unroll
    for (int g = 0; g < 4; ++g) {
        *(float4*)&P[base + 4*g]  = make_float4(accp[4*g], accp[4*g+1], accp[4*g+2], accp[4*g+3]);
        *(float4*)&Dd[base + 4*g] = make_float4(accd[4*g], accd[4*g+1], accd[4*g+2], accd[4*g+3]);
    }
}

// ---------------- kernel 4: BN stats -> per-block partials ----------------
__global__ __launch_bounds__(256) void stats_kernel(const float* __restrict__ P,
                                                    const float* __restrict__ Dd,
                                                    const unsigned short* __restrict__ idx,
                                                    double* __restrict__ partials) {
    const int tid = threadIdx.x;
    const int o = tid & 63, g = tid >> 6;
    const int row0 = blockIdx.x * 32;
    double s1 = 0.0, s2 = 0.0;
    for (int i = 0; i < 8; ++i) {
        int row = row0 + g + 4 * i;
        int b = row >> 12;
        float d = Dd[(size_t)row * OO + o];
        const unsigned short* ip = idx + (size_t)row * KK;
        const float* Pb = P + ((size_t)b * NN) * OO;
#pragma unroll
        for (int k = 0; k < KK; ++k) {
            int j = ip[k];
            float y = Pb[(size_t)j * OO + o] + d;
            s1 += (double)y;
            s2 += (double)y * (double)y;
        }
    }
    __shared__ double r1[4][64];
    __shared__ double r2[4][64];
    r1[g][o] = s1; r2[g][o] = s2;
    __syncthreads();
    if (g == 0) {
        double a1 = r1[0][o] + r1[1][o] + r1[2][o] + r1[3][o];
        double a2 = r2[0][o] + r2[1][o] + r2[2][o] + r2[3][o];
        partials[(size_t)blockIdx.x * 128 + o]      = a1;
        partials[(size_t)blockIdx.x * 128 + 64 + o] = a2;
    }
}

// ---------------- kernel 5: reduce partials + finalize scale/shift ----------------
#define NSTATB (BB * NN / 32)
__global__ void finalize_kernel(const double* __restrict__ partials,
                                const float* __restrict__ gamma,
                                const float* __restrict__ beta,
                                float* __restrict__ ss) {
    int o = threadIdx.x;  // 64 threads
    double s1 = 0.0, s2 = 0.0;
    for (int blk = 0; blk < NSTATB; ++blk) {
        s1 += partials[(size_t)blk * 128 + o];
        s2 += partials[(size_t)blk * 128 + 64 + o];
    }
    const double cnt = (double)BB * NN * KK;
    double mean = s1 / cnt;
    double var = s2 / cnt - mean * mean;
    double rs = 1.0 / sqrt(var + 1e-5);
    double sc = (double)gamma[o] * rs;
    ss[o] = (float)sc;
    ss[64 + o] = (float)((double)beta[o] - mean * sc);
}

// ---------------- kernel 6: gather + BN affine + LeakyReLU + max_k + transpose ----------------
__global__ __launch_bounds__(256) void out_kernel(const float* __restrict__ P,
                                                  const float* __restrict__ Dd,
                                                  const unsigned short* __restrict__ idx,
                                                  const float* __restrict__ ss,
                                                  float* __restrict__ out) {
    __shared__ float tile[32][65];
    const int tid = threadIdx.x;
    const int o = tid & 63, g = tid >> 6;
    const int b = blockIdx.y;
    const int n0 = blockIdx.x * 32;
    const float sc = ss[o], sh = ss[64 + o];
    const float* Pb = P + ((size_t)b * NN) * OO;
    for (int i = 0; i < 8; ++i) {
        int nl = g + 4 * i;
        int row = b * NN + n0 + nl;
        float d = Dd[(size_t)row * OO + o];
        const unsigned short* ip = idx + (size_t)row * KK;
        float mv = -__builtin_inff();
#pragma unroll
        for (int k = 0; k < KK; ++k) {
            int j = ip[k];
            float y = Pb[(size_t)j * OO + o] + d;
            float t = y * sc + sh;
            t = (t >= 0.f) ? t : 0.2f * t;
            mv = fmaxf(mv, t);
        }
        tile[nl][o] = mv;
    }
    __syncthreads();
    const int nn = tid & 31, og = tid >> 5;   // 8 o-rows per pass
    for (int i = 0; i < 8; ++i) {
        int oo = og + 8 * i;
        out[((size_t)b * OO + oo) * NN + n0 + nn] = tile[nn][oo];
    }
}

// ---------------- launch ----------------
extern "C" void kernel_launch(void* const* d_in, const int* in_sizes, int n_in,
                              void* d_out, int out_size, void* d_ws, size_t ws_size,
                              hipStream_t stream) {
    (void)in_sizes; (void)n_in; (void)out_size; (void)ws_size;
    const float* x     = (const float*)d_in[0];   // [B, C, N]
    const float* W     = (const float*)d_in[1];   // [O, 2C]
    const float* gamma = (const float*)d_in[2];   // [O]
    const float* beta  = (const float*)d_in[3];   // [O]
    float* out = (float*)d_out;                   // [B, O, N] fp32

    // Workspace, phase-overlapped (peak ~22.2 MB):
    //   xx       @ 0           128 KB  (transpose -> merge)
    //   xT       @ 131,072     8 MB    (transpose -> merge)  -> P        (pd -> end)
    //   xTh      @ 8,519,680   4 MB    (transpose -> collect)-> idx      (merge -> end)
    //   gmaxG    @ 12,713,984  4 MB    (gmax -> thresh)
    //   cand     @ 12,713,984  8 MB    (collect -> merge)    -> Dd       (pd -> end)
    //   Tg       @ 21,102,592  128 KB  (thresh -> collect)   -> partials (stats ..)
    //   cntS     @ 21,233,664  512 KB  (collect -> merge)    -> partials
    //   ss       @ 22,151,168  512 B
    char* ws = (char*)d_ws;
    float*          xx       = (float*)ws;
    float*          xT       = (float*)(ws + 131072);
    unsigned int*   xTh      = (unsigned int*)(ws + 8519680);
    float*          gmaxG    = (float*)(ws + 12713984);
    unsigned short* cand     = (unsigned short*)(ws + 12713984);
    float*          Tg       = (float*)(ws + 21102592);
    unsigned int*   cntS     = (unsigned int*)(ws + 21233664);
    unsigned short* idx      = (unsigned short*)(ws + 8519680);
    float*          P        = (float*)(ws + 131072);
    float*          Dd       = (float*)(ws + 12713984);
    double*         partials = (double*)(ws + 21102592);
    float*          ss       = (float*)(ws + 22151168);

    transpose_kernel<<<dim3(NN / 64 + 16, BB), 256, 0, stream>>>(x, xT, xTh, xx);
    knn_gmax_kernel<<<dim3(NN / 256, GSPLIT, BB), 256, 0, stream>>>(xTh, xx, gmaxG);
    knn_thresh_kernel<<<dim3(BN / 256), 256, 0, stream>>>(gmaxG, Tg);
    knn_collect_kernel<<<dim3(NN / 128, CSPLIT, BB), 256, 0, stream>>>(xTh, xx, Tg, cand, cntS);
    knn_merge_kernel<<<dim3(BN / 4), 256, 0, stream>>>(xT, xx, cand, cntS, idx);
    pd_kernel<<<dim3(NN / 256, BB, 4), 256, 0, stream>>>(x, W, P, Dd);
    stats_kernel<<<dim3(BN / 32), 256, 0, stream>>>(P, Dd, idx, partials);
    finalize_kernel<<<1, 64, 0, stream>>>(partials, gamma, beta, ss);
    out_kernel<<<dim3(NN / 32, BB), 256, 0, stream>>>(P, Dd, idx, ss, out);
}

// Round 17
// 322.395 us; speedup vs baseline: 1.1040x; 1.0089x over previous
//
#include <hip/hip_runtime.h>
#include <cstdint>
#include <cstddef>

#define BB 8
#define CC 64
#define NN 4096
#define OO 64
#define KK 20
#define TWO_C 128
#define BN (BB * NN)

#define GSPLIT 16            // j-range split for gmax (256 j per block)
#define GJPB (NN / GSPLIT)
#define JCH 128              // collect: j-chunk staged in LDS
#define CSPLIT 8             // j-range split for collect (= cand segments); 2048 blocks
#define CJPB (NN / CSPLIT)
#define SEGCAP 24            // per-row per-segment capacity (Poisson(3.9): P(>24) ~ 1e-12)

typedef float vf4 __attribute__((ext_vector_type(4)));
typedef float f4  __attribute__((ext_vector_type(4)));
typedef _Float16 hf2 __attribute__((ext_vector_type(2)));
typedef _Float16 h8  __attribute__((ext_vector_type(8)));

__device__ __forceinline__ unsigned int pack_h2(float a, float b) {
    hf2 h; h.x = (_Float16)a; h.y = (_Float16)b;
    return __builtin_bit_cast(unsigned int, h);
}

// Monotone float->uint map: a > b (float) <=> mu(a) > mu(b) (uint)
__device__ __forceinline__ unsigned int fmap(float d) {
    unsigned int s = __float_as_uint(d);
    return s ^ (unsigned int)(((int)s >> 31) | 0x80000000);
}

// Bitonic compare-exchange across lanes (u64 keys), direction per k-block.
__device__ __forceinline__ unsigned long long cmpx(unsigned long long key, int lane, int j, bool dirDesc) {
    unsigned long long o = __shfl_xor(key, j, 64);
    bool lower = (lane & j) == 0;
    bool takeMax = (dirDesc == lower);
    return ((o > key) == takeMax) ? o : key;
}

// ---------------- kernel 0: transpose + f16 packing (+ xx role, grid-concat) ----------------
__global__ __launch_bounds__(256) void transpose_kernel(const float* __restrict__ x,
                                                        float* __restrict__ xT,
                                                        unsigned int* __restrict__ xTh,
                                                        float* __restrict__ xx) {
    __shared__ float t[64][65];
    const int tid = threadIdx.x;
    if (blockIdx.x >= NN / 64) {   // ---- xx role: 16 x-cols x 8 y = 128 blocks
        int q = (blockIdx.x - NN / 64) * BB + blockIdx.y;   // [0,128)
        int tt2 = q * 256 + tid;                            // [0, B*N)
        int b = tt2 >> 12, n = tt2 & (NN - 1);
        const float* xp = x + (size_t)b * CC * NN + n;
        float acc = 0.f;
#pragma unroll
        for (int c = 0; c < CC; ++c) {
            float v = xp[(size_t)c * NN];
            acc += v * v;
        }
        xx[tt2] = acc;
        return;
    }
    const int b = blockIdx.y;
    const int n0 = blockIdx.x * 64;
    const int ln = tid & 63, g = tid >> 6;
#pragma unroll
    for (int i = 0; i < 16; ++i) {
        int c = g * 16 + i;
        t[c][ln] = x[((size_t)b * CC + c) * NN + n0 + ln];
    }
    __syncthreads();
#pragma unroll
    for (int i = 0; i < 16; ++i) {
        int nl = g * 16 + i;
        xT[((size_t)b * NN + n0 + nl) * CC + ln] = t[ln][nl];
    }
#pragma unroll
    for (int it = 0; it < 8; ++it) {
        int e = it * 256 + tid;           // 0..2047
        int nl = e >> 5, cp = e & 31;
        xTh[((size_t)b * NN + n0 + nl) * 32 + cp] = pack_h2(t[2*cp][nl], t[2*cp+1][nl]);
    }
}

// ---------------- kernel 2a: LDS-free streaming MFMA -> per-row group maxima ----------------
__global__ __launch_bounds__(256) void knn_gmax_kernel(const unsigned int* __restrict__ xTh,
                                                       const float* __restrict__ xx,
                                                       float* __restrict__ gmaxG) {
    const int tid = threadIdx.x;
    const int wv = tid >> 6, lane = tid & 63;
    const int lcol = lane & 15, lrow = lane >> 4;
    const int b = blockIdx.z;
    const int i0w = blockIdx.x * 256 + wv * 64;   // this wave's 64 rows
    const int j0 = blockIdx.y * GJPB;             // 256 j
    const unsigned int* xb = xTh + (size_t)b * NN * 32;
    const float* xxb = xx + (size_t)b * NN;

    uint4 A0[4], A1[4];
#pragma unroll
    for (int s = 0; s < 4; ++s) {
        const uint4* ap = (const uint4*)(xb + (size_t)(i0w + s * 16 + lcol) * 32 + lrow * 4);
        A0[s] = ap[0]; A1[s] = ap[4];             // k 0..31 / 32..63
    }

    int g = j0 >> 7;
    for (int gg = 0; gg < GJPB / 128; ++gg, ++g) {
        float m[16];
#pragma unroll
        for (int s = 0; s < 16; ++s) m[s] = -3.4e38f;
#pragma unroll
        for (int jt = 0; jt < 8; ++jt) {
            const int jj = j0 + gg * 128 + jt * 16 + lcol;
            const uint4* bp = (const uint4*)(xb + (size_t)jj * 32 + lrow * 4);
            uint4 B0 = bp[0], B1 = bp[4];
            float h = 0.5f * xxb[jj];
#pragma unroll
            for (int s = 0; s < 4; ++s) {
                f4 acc = {0.f, 0.f, 0.f, 0.f};
                acc = __builtin_amdgcn_mfma_f32_16x16x32_f16(__builtin_bit_cast(h8, A0[s]), __builtin_bit_cast(h8, B0), acc, 0, 0, 0);
                acc = __builtin_amdgcn_mfma_f32_16x16x32_f16(__builtin_bit_cast(h8, A1[s]), __builtin_bit_cast(h8, B1), acc, 0, 0, 0);
#pragma unroll
                for (int r = 0; r < 4; ++r)
                    m[s * 4 + r] = fmaxf(m[s * 4 + r], acc[r] - h);
            }
        }
        // group of 128 j complete: reduce across the 16 lcol lanes, f4 stores
#pragma unroll
        for (int s = 0; s < 16; ++s) {
#pragma unroll
            for (int off = 1; off < 16; off <<= 1)
                m[s] = fmaxf(m[s], __shfl_xor(m[s], off));
        }
        if (lcol == 0) {
            int r0 = b * NN + i0w + lrow * 4;
#pragma unroll
            for (int s = 0; s < 4; ++s) {
                f4 mv; mv[0] = m[4*s]; mv[1] = m[4*s+1]; mv[2] = m[4*s+2]; mv[3] = m[4*s+3];
                *(f4*)&gmaxG[(size_t)g * BN + r0 + s * 16] = mv;
            }
        }
    }
}

// ---------------- kernel 2b: per-row threshold = 20th-largest of 32 group maxima ----------------
// Order-stat: the 20 group-maxima >= T are 20 distinct elements => T <= 20th-
// largest overall, so collecting d >= T can never miss a top-20 element.
__global__ __launch_bounds__(256) void knn_thresh_kernel(const float* __restrict__ gmaxG,
                                                         float* __restrict__ Tg) {
    const int row = blockIdx.x * 256 + threadIdx.x;   // [0, B*N)
    float L[KK];
#pragma unroll
    for (int s = 0; s < KK; ++s) L[s] = -3.4e38f;
#pragma unroll
    for (int g = 0; g < 32; ++g) {
        float xv = gmaxG[(size_t)g * BN + row];
#pragma unroll
        for (int s = 0; s < KK; ++s) {
            float hi = fmaxf(xv, L[s]);
            xv = fminf(xv, L[s]);
            L[s] = hi;
        }
    }
    Tg[row] = L[KK - 1];
}

// ---------------- kernel 2c: staged recompute + BALLOT collect of j with d >= T[row] ----------------
// R16's proven code; CSPLIT 4->8 removes the grid cap (1024 -> 2048 blocks;
// R16 was exactly 4 blocks/CU grid-limited) without adding staging traffic
// (each (i0,b) tile still covers all NN j exactly once across its segments;
// R15 showed halving ROWS doubles staging — the j-split axis is free).
// SEGCAP 24: bufL 6KB -> LDS 25.1KB -> 6 blocks/CU. Overflow P ~ 1e-12, and
// still exact via merge's exhaustive guard. Empty-ballot skip (~61%) kept.
__global__ __launch_bounds__(256) void knn_collect_kernel(const unsigned int* __restrict__ xTh,
                                                          const float* __restrict__ xx,
                                                          const float* __restrict__ Tg,
                                                          unsigned short* __restrict__ cand,
                                                          unsigned int* __restrict__ cntS) {
    __shared__ unsigned int stage[JCH * 36];       // 18 KB: 128 j x 32 words, stride 36
    __shared__ float xxh[JCH];
    __shared__ unsigned short bufL[128][SEGCAP];   // 6 KB
    const int tid = threadIdx.x;
    const int wv = tid >> 6, lane = tid & 63;
    const int lcol = lane & 15, lrow = lane >> 4;
    const int b = blockIdx.z;
    const int i0 = blockIdx.x * 128;
    const int i0w = i0 + wv * 32;
    const int seg = blockIdx.y;
    const int j0 = seg * CJPB;                     // 512 j
    const unsigned int* xb = xTh + (size_t)b * NN * 32;
    const float* xxb = xx + (size_t)b * NN;

    uint4 A0[2], A1[2];
    f4 tt[2];
#pragma unroll
    for (int s = 0; s < 2; ++s) {
        const uint4* ap = (const uint4*)(xb + (size_t)(i0w + s * 16 + lcol) * 32 + lrow * 4);
        A0[s] = ap[0]; A1[s] = ap[4];
        tt[s] = *(const f4*)&Tg[b * NN + i0w + s * 16 + lrow * 4];
    }

    unsigned int cnt[2][4];
#pragma unroll
    for (int s = 0; s < 2; ++s)
#pragma unroll
        for (int r = 0; r < 4; ++r) cnt[s][r] = 0;

    uint4 pf[4];
    float pxx;
    {
        const uint4* src = (const uint4*)(xb + (size_t)j0 * 32);
#pragma unroll
        for (int gi = 0; gi < 4; ++gi) pf[gi] = src[gi * 256 + tid];
        pxx = xxb[j0 + (tid & 127)];
    }

    for (int jc = j0; jc < j0 + CJPB; jc += JCH) {
        __syncthreads();   // prior chunk's readers done
#pragma unroll
        for (int gi = 0; gi < 4; ++gi) {
            int e4 = gi * 256 + tid;
            *(uint4*)&stage[(e4 >> 3) * 36 + (e4 & 7) * 4] = pf[gi];
        }
        if (tid < JCH) xxh[tid] = 0.5f * pxx;
        __syncthreads();   // stage ready
        if (jc + JCH < j0 + CJPB) {
            const uint4* src = (const uint4*)(xb + (size_t)(jc + JCH) * 32);
#pragma unroll
            for (int gi = 0; gi < 4; ++gi) pf[gi] = src[gi * 256 + tid];
            pxx = xxb[jc + JCH + (tid & 127)];
        }
#pragma unroll
        for (int jt = 0; jt < 8; ++jt) {
            const uint4* bp = (const uint4*)&stage[(jt * 16 + lcol) * 36 + lrow * 4];
            uint4 B0 = bp[0], B1 = bp[4];
            float h = xxh[jt * 16 + lcol];
            const int jj = jc + jt * 16 + lcol;
#pragma unroll
            for (int s = 0; s < 2; ++s) {
                f4 acc = {0.f, 0.f, 0.f, 0.f};
                acc = __builtin_amdgcn_mfma_f32_16x16x32_f16(__builtin_bit_cast(h8, A0[s]), __builtin_bit_cast(h8, B0), acc, 0, 0, 0);
                acc = __builtin_amdgcn_mfma_f32_16x16x32_f16(__builtin_bit_cast(h8, A1[s]), __builtin_bit_cast(h8, B1), acc, 0, 0, 0);
#pragma unroll
                for (int r = 0; r < 4; ++r) {
                    bool hit = (acc[r] - h >= tt[s][r]);
                    unsigned long long mask = __ballot(hit);
                    if (mask) {   // wave-uniform skip of empty ballots (~61%)
                        unsigned int grp = (unsigned int)(mask >> (lrow * 16)) & 0xFFFFu;
                        unsigned int pos = cnt[s][r] + (unsigned int)__popc(grp & ((1u << lcol) - 1u));
                        int rl = wv * 32 + s * 16 + lrow * 4 + r;
                        if (hit && pos < SEGCAP) bufL[rl][pos] = (unsigned short)jj;
                        cnt[s][r] += (unsigned int)__popc(grp);
                    }
                }
            }
        }
    }
    // per-row counts (uniform within each 16-lane group): lane lcol==0 writes
    if (lcol == 0) {
#pragma unroll
        for (int s = 0; s < 2; ++s)
#pragma unroll
            for (int r = 0; r < 4; ++r)
                cntS[(size_t)seg * BN + b * NN + i0 + wv * 32 + s * 16 + lrow * 4 + r] = cnt[s][r];
    }
    __syncthreads();
    // coalesced copy-out of this block's private segment (128 rows x 24 shorts)
    const unsigned int* bl = (const unsigned int*)&bufL[0][0];
    unsigned int* cd = (unsigned int*)(cand + ((size_t)seg * BN + b * NN + i0) * SEGCAP);
#pragma unroll
    for (int e = tid; e < 128 * SEGCAP / 2; e += 256) cd[e] = bl[e];
}

// ---------------- kernel 2d: wave-per-row exact re-rank -> top-20 (R6 fused form) ----------------
// One 64-lane wave per row: lane l owns candidate l (one gather + 64 fmaf,
// fully parallel), then a 64-lane bitonic sort of total-order u64 keys
// (fmap(d)<<32 | 4095-j == lax.top_k tie semantics). Branchless single-load
// 8-segment lookup (R8-proven cost-neutral). totals in (64,128] -> 2 keys/lane
// bitonic-128. Any segment > SEGCAP or total > 128 -> exhaustive (exact;
// P ~ 1e-12 on this input).
__global__ __launch_bounds__(256) void knn_merge_kernel(const float* __restrict__ xT,
                                                        const float* __restrict__ xx,
                                                        const unsigned short* __restrict__ cand,
                                                        const unsigned int* __restrict__ cntS,
                                                        unsigned short* __restrict__ idx_out) {
    const int tid = threadIdx.x;
    const int wv = tid >> 6, lane = tid & 63;
    const int rr = __builtin_amdgcn_readfirstlane(blockIdx.x * 4 + wv);  // row [0, B*N)
    const int b = rr >> 12, i = rr & (NN - 1);
    const float* xTb = xT + (size_t)b * NN * CC;
    const float* xxb = xx + b * NN;

    vf4 xiv[CC / 4];
    const float* xip = xTb + (size_t)i * CC;
#pragma unroll
    for (int c4 = 0; c4 < CC / 4; ++c4) xiv[c4] = *(const vf4*)(xip + 4 * c4);

    unsigned int cs[CSPLIT];
    bool segovf = false;
    unsigned int total = 0;
#pragma unroll
    for (int s = 0; s < CSPLIT; ++s) {
        cs[s] = cntS[(size_t)s * BN + rr];
        segovf |= (cs[s] > SEGCAP);
        total += cs[s];
    }
    segovf |= (total > 128);

    auto dot_key = [&](int jj) -> unsigned long long {
        const float* xj = xTb + (size_t)jj * CC;
        float a0 = 0.f, a1 = 0.f, a2 = 0.f, a3 = 0.f;
#pragma unroll
        for (int c4 = 0; c4 < CC / 4; ++c4) {
            vf4 xjv = *(const vf4*)(xj + 4 * c4);
            a0 = fmaf(xiv[c4].x, xjv.x, a0);
            a1 = fmaf(xiv[c4].y, xjv.y, a1);
            a2 = fmaf(xiv[c4].z, xjv.z, a2);
            a3 = fmaf(xiv[c4].w, xjv.w, a3);
        }
        float d = 2.f * ((a0 + a1) + (a2 + a3)) - xxb[jj];
        return ((unsigned long long)fmap(d) << 32) | (unsigned int)(NN - 1 - jj);
    };

    // Branchless: select-chain computes the flat cand offset, then ONE load.
    auto fetch_key = [&](unsigned int l) -> unsigned long long {
        if (l >= total) return 0ull;
        unsigned int base = 0, addr = 0;
#pragma unroll
        for (int s = 0; s < CSPLIT; ++s) {
            unsigned int lo = base;
            base += cs[s];
            unsigned int a = ((unsigned int)s * (unsigned int)BN + (unsigned int)rr) * SEGCAP + (l - lo);
            bool in = (l >= lo) & (l < base);
            addr = in ? a : addr;
        }
        return dot_key((int)cand[addr]);
    };

    unsigned long long kout;
    if (!segovf && total <= 64) {
        unsigned long long key = fetch_key((unsigned int)lane);
        // bitonic sort 64, descending
#pragma unroll
        for (int k = 2; k <= 64; k <<= 1) {
            bool dir = (lane & k) == 0;
#pragma unroll
            for (int j = k >> 1; j > 0; j >>= 1) key = cmpx(key, lane, j, dir);
        }
        kout = key;
    } else if (!segovf) {          // 64 < total <= 128
        unsigned long long key  = fetch_key((unsigned int)lane);
        unsigned long long key2 = fetch_key((unsigned int)lane + 64);
        // bitonic sort 128 (elements: e = lane for key, e = 64+lane for key2)
#pragma unroll
        for (int k = 2; k <= 64; k <<= 1) {
            bool dir0 = (lane & k) == 0;
            bool dir1 = (k == 64) ? false : dir0;   // (e1 & 64) = 64 at k=64
#pragma unroll
            for (int j = k >> 1; j > 0; j >>= 1) {
                key  = cmpx(key,  lane, j, dir0);
                key2 = cmpx(key2, lane, j, dir1);
            }
        }
        // k = 128 (dir = descending for all): j = 64 is the in-lane pair
        {
            unsigned long long mx = key2 > key ? key2 : key;
            unsigned long long mn = key2 > key ? key : key2;
            key = mx; key2 = mn;
        }
#pragma unroll
        for (int j = 32; j > 0; j >>= 1) {
            key  = cmpx(key,  lane, j, true);
            key2 = cmpx(key2, lane, j, true);
        }
        kout = key;
    } else {
        // exhaustive: rounds of 64 j's; running top-64 in `run` (desc). Exact.
        unsigned long long run = 0ull;
        for (int t = 0; t < NN / 64; ++t) {
            unsigned long long key = dot_key(t * 64 + lane);
#pragma unroll
            for (int k = 2; k <= 64; k <<= 1) {
                bool dir = (lane & k) == 0;
#pragma unroll
                for (int j = k >> 1; j > 0; j >>= 1) key = cmpx(key, lane, j, dir);
            }
            // merge: [key desc | rev(run) asc] is bitonic-128; keep top half
            unsigned long long rev = __shfl(run, 63 - lane, 64);
            key = key > rev ? key : rev;
#pragma unroll
            for (int j = 32; j > 0; j >>= 1) key = cmpx(key, lane, j, true);
            run = key;
        }
        kout = run;
    }

    if (lane < KK)
        idx_out[(size_t)rr * KK + lane] =
            (unsigned short)(NN - 1 - (unsigned int)(kout & 0xFFFFFFFFull));
}

// ---------------- kernel 3: P = xt*W1^T, D = xt*(W2-W1)^T ----------------
// o split 4 ways (z=4): 16 outputs/thread (32 acc VGPR), grid 512 = 2/CU.
__global__ __launch_bounds__(256) void pd_kernel(const float* __restrict__ x,
                                                 const float* __restrict__ W,
                                                 float* __restrict__ P,
                                                 float* __restrict__ Dd) {
    __shared__ float w1T[CC][16];
    __shared__ float wdT[CC][16];
    const int tid = threadIdx.x;
    const int b = blockIdx.y;
    const int o0 = blockIdx.z * 16;
    for (int e = tid; e < 16 * CC; e += 256) {
        int ol = e >> 6, c = e & 63;
        float w1 = W[(o0 + ol) * TWO_C + c];
        float w2 = W[(o0 + ol) * TWO_C + CC + c];
        w1T[c][ol] = w1;
        wdT[c][ol] = w2 - w1;
    }
    __syncthreads();
    const int n = blockIdx.x * 256 + tid;
    float accp[16], accd[16];
#pragma unroll
    for (int i = 0; i < 16; ++i) { accp[i] = 0.f; accd[i] = 0.f; }
    const float* xp = x + (size_t)b * CC * NN + n;
    for (int c = 0; c < CC; ++c) {
        float xv = xp[(size_t)c * NN];
        const float4* w1r = (const float4*)&w1T[c][0];
        const float4* wdr = (const float4*)&wdT[c][0];
#pragma unroll
        for (int g = 0; g < 4; ++g) {
            float4 aw = w1r[g]; float4 bw = wdr[g];
            accp[4*g+0] += xv * aw.x; accp[4*g+1] += xv * aw.y;
            accp[4*g+2] += xv * aw.z; accp[4*g+3] += xv * aw.w;
            accd[4*g+0] += xv * bw.x; accd[4*g+1] += xv * bw.y;
            accd[4*g+2] += xv * bw.z; accd[4*g+3] += xv * bw.w;
        }
    }
    size_t base = ((size_t)b * NN + n) * OO + o0;
#pragma unroll
    for (int g = 0; g < 4; ++g) {
        *(float4*)&P[base + 4*g]  = make_float4(accp[4*g], accp[4*g+1], accp[4*g+2], accp[4*g+3]);
        *(float4*)&Dd[base + 4*g] = make_float4(accd[4*g], accd[4*g+1], accd[4*g+2], accd[4*g+3]);
    }
}

// ---------------- kernel 4: BN stats -> per-block partials ----------------
__global__ __launch_bounds__(256) void stats_kernel(const float* __restrict__ P,
                                                    const float* __restrict__ Dd,
                                                    const unsigned short* __restrict__ idx,
                                                    double* __restrict__ partials) {
    const int tid = threadIdx.x;
    const int o = tid & 63, g = tid >> 6;
    const int row0 = blockIdx.x * 32;
    double s1 = 0.0, s2 = 0.0;
    for (int i = 0; i < 8; ++i) {
        int row = row0 + g + 4 * i;
        int b = row >> 12;
        float d = Dd[(size_t)row * OO + o];
        const unsigned short* ip = idx + (size_t)row * KK;
        const float* Pb = P + ((size_t)b * NN) * OO;
#pragma unroll
        for (int k = 0; k < KK; ++k) {
            int j = ip[k];
            float y = Pb[(size_t)j * OO + o] + d;
            s1 += (double)y;
            s2 += (double)y * (double)y;
        }
    }
    __shared__ double r1[4][64];
    __shared__ double r2[4][64];
    r1[g][o] = s1; r2[g][o] = s2;
    __syncthreads();
    if (g == 0) {
        double a1 = r1[0][o] + r1[1][o] + r1[2][o] + r1[3][o];
        double a2 = r2[0][o] + r2[1][o] + r2[2][o] + r2[3][o];
        partials[(size_t)blockIdx.x * 128 + o]      = a1;
        partials[(size_t)blockIdx.x * 128 + 64 + o] = a2;
    }
}

// ---------------- kernel 5: reduce partials + finalize scale/shift ----------------
#define NSTATB (BB * NN / 32)
__global__ void finalize_kernel(const double* __restrict__ partials,
                                const float* __restrict__ gamma,
                                const float* __restrict__ beta,
                                float* __restrict__ ss) {
    int o = threadIdx.x;  // 64 threads
    double s1 = 0.0, s2 = 0.0;
    for (int blk = 0; blk < NSTATB; ++blk) {
        s1 += partials[(size_t)blk * 128 + o];
        s2 += partials[(size_t)blk * 128 + 64 + o];
    }
    const double cnt = (double)BB * NN * KK;
    double mean = s1 / cnt;
    double var = s2 / cnt - mean * mean;
    double rs = 1.0 / sqrt(var + 1e-5);
    double sc = (double)gamma[o] * rs;
    ss[o] = (float)sc;
    ss[64 + o] = (float)((double)beta[o] - mean * sc);
}

// ---------------- kernel 6: gather + BN affine + LeakyReLU + max_k + transpose ----------------
__global__ __launch_bounds__(256) void out_kernel(const float* __restrict__ P,
                                                  const float* __restrict__ Dd,
                                                  const unsigned short* __restrict__ idx,
                                                  const float* __restrict__ ss,
                                                  float* __restrict__ out) {
    __shared__ float tile[32][65];
    const int tid = threadIdx.x;
    const int o = tid & 63, g = tid >> 6;
    const int b = blockIdx.y;
    const int n0 = blockIdx.x * 32;
    const float sc = ss[o], sh = ss[64 + o];
    const float* Pb = P + ((size_t)b * NN) * OO;
    for (int i = 0; i < 8; ++i) {
        int nl = g + 4 * i;
        int row = b * NN + n0 + nl;
        float d = Dd[(size_t)row * OO + o];
        const unsigned short* ip = idx + (size_t)row * KK;
        float mv = -__builtin_inff();
#pragma unroll
        for (int k = 0; k < KK; ++k) {
            int j = ip[k];
            float y = Pb[(size_t)j * OO + o] + d;
            float t = y * sc + sh;
            t = (t >= 0.f) ? t : 0.2f * t;
            mv = fmaxf(mv, t);
        }
        tile[nl][o] = mv;
    }
    __syncthreads();
    const int nn = tid & 31, og = tid >> 5;   // 8 o-rows per pass
    for (int i = 0; i < 8; ++i) {
        int oo = og + 8 * i;
        out[((size_t)b * OO + oo) * NN + n0 + nn] = tile[nn][oo];
    }
}

// ---------------- launch ----------------
extern "C" void kernel_launch(void* const* d_in, const int* in_sizes, int n_in,
                              void* d_out, int out_size, void* d_ws, size_t ws_size,
                              hipStream_t stream) {
    (void)in_sizes; (void)n_in; (void)out_size; (void)ws_size;
    const float* x     = (const float*)d_in[0];   // [B, C, N]
    const float* W     = (const float*)d_in[1];   // [O, 2C]
    const float* gamma = (const float*)d_in[2];   // [O]
    const float* beta  = (const float*)d_in[3];   // [O]
    float* out = (float*)d_out;                   // [B, O, N] fp32

    // Workspace, phase-overlapped (peak ~26.5 MB; <= 29.5 MB proven envelope):
    //   xx       @ 0           128 KB  (transpose -> merge)
    //   xT       @ 131,072     8 MB    (transpose -> merge)  -> P        (pd -> end)
    //   xTh      @ 8,519,680   4 MB    (transpose -> collect)-> idx      (merge -> end)
    //   gmaxG    @ 12,713,984  4 MB    (gmax -> thresh)
    //   cand     @ 12,713,984  12.58MB (collect -> merge)    -> Dd 8MB   (pd -> end)
    //   Tg       @ 25,296,896  128 KB  (thresh -> collect)   -> partials (stats ..)
    //   cntS     @ 25,427,968  1 MB    (collect -> merge)    -> partials
    //   ss       @ 26,476,544  512 B   (finalize -> out)
    char* ws = (char*)d_ws;
    float*          xx       = (float*)ws;
    float*          xT       = (float*)(ws + 131072);
    unsigned int*   xTh      = (unsigned int*)(ws + 8519680);
    float*          gmaxG    = (float*)(ws + 12713984);
    unsigned short* cand     = (unsigned short*)(ws + 12713984);
    float*          Tg       = (float*)(ws + 25296896);
    unsigned int*   cntS     = (unsigned int*)(ws + 25427968);
    unsigned short* idx      = (unsigned short*)(ws + 8519680);
    float*          P        = (float*)(ws + 131072);
    float*          Dd       = (float*)(ws + 12713984);
    double*         partials = (double*)(ws + 25296896);
    float*          ss       = (float*)(ws + 26476544);

    transpose_kernel<<<dim3(NN / 64 + 16, BB), 256, 0, stream>>>(x, xT, xTh, xx);
    knn_gmax_kernel<<<dim3(NN / 256, GSPLIT, BB), 256, 0, stream>>>(xTh, xx, gmaxG);
    knn_thresh_kernel<<<dim3(BN / 256), 256, 0, stream>>>(gmaxG, Tg);
    knn_collect_kernel<<<dim3(NN / 128, CSPLIT, BB), 256, 0, stream>>>(xTh, xx, Tg, cand, cntS);
    knn_merge_kernel<<<dim3(BN / 4), 256, 0, stream>>>(xT, xx, cand, cntS, idx);
    pd_kernel<<<dim3(NN / 256, BB, 4), 256, 0, stream>>>(x, W, P, Dd);
    stats_kernel<<<dim3(BN / 32), 256, 0, stream>>>(P, Dd, idx, partials);
    finalize_kernel<<<1, 64, 0, stream>>>(partials, gamma, beta, ss);
    out_kernel<<<dim3(NN / 32, BB), 256, 0, stream>>>(P, Dd, idx, ss, out);
}